// Round 1
// baseline (378.723 us; speedup 1.0000x reference)
//
#include <hip/hip_runtime.h>

#define N_NODES 50000
#define N_EDGES 640000
#define N_SUP   3
#define D       128
#define NTOT    150000                   // 3 * 50000 global rows
#define E_TOT   1920000
#define NC      293                      // 512-row buckets (grow>>9)
#define CAPB    9216                     // per-bucket slot stride (mean 6553, +32 sigma)
#define CBLKS   938                      // ceil(E_TOT / 2048) count/place blocks
#define XCBLKS  3125                     // (50000*128/4)/512 x-convert blocks
#define WBLKS   96                       // 49152/512 W-pack blocks
#define LDSTR   132                      // LDS row stride in shorts (128+4 pad)

typedef __attribute__((ext_vector_type(2))) float f32x2;
typedef __attribute__((ext_vector_type(4))) float f32x4;
typedef __attribute__((ext_vector_type(8))) short s16x8;

__device__ __forceinline__ unsigned short f2bf(float f) {   // RNE
    unsigned int u = __float_as_uint(f);
    u += 0x7FFFu + ((u >> 16) & 1u);
    return (unsigned short)(u >> 16);
}

// ---------------------------------------------------------------------------
// Pass 1: per-row edge COUNT (diffuse atomics over 150K counters — no hot
// cachelines, unlike the old 512-counter coarse_wptr), fused with the x->bf16
// and W->fragment converts (unchanged from the previous version).
// ---------------------------------------------------------------------------
__global__ __launch_bounds__(512) void count_convert(
    const int* __restrict__ rows, int* __restrict__ row_cnt,
    const float4* __restrict__ x, ushort4* __restrict__ xb,
    const float* __restrict__ W, unsigned short* __restrict__ Wf)
{
    int tid = threadIdx.x;

    if (blockIdx.x < CBLKS) {                    // -------- count path ------
        int base = blockIdx.x * 2048 + tid;
        #pragma unroll
        for (int i = 0; i < 4; ++i) {
            int idx = base + i * 512;
            if (idx < E_TOT) {
                int s = idx / N_EDGES;           // magic-mul, cheap
                atomicAdd(&row_cnt[s * N_NODES + rows[idx]], 1);
            }
        }
        return;
    }

    int gid = (blockIdx.x - CBLKS) * 512 + tid;  // -------- convert path ----
    if (gid < N_NODES * D / 4) {                 // x -> bf16
        float4 v = x[gid];
        ushort4 o;
        o.x = f2bf(v.x); o.y = f2bf(v.y); o.z = f2bf(v.z); o.w = f2bf(v.w);
        xb[gid] = o;
    } else {                                     // W -> MFMA B-fragment order
        int g2 = gid - N_NODES * D / 4;
        if (g2 < N_SUP * D * D) {
            int j    = g2 & 7;
            int lane = (g2 >> 3) & 63;
            int rest = g2 >> 9;
            int nt = rest & 7, kb = (rest >> 3) & 3, s = rest >> 5;
            int k = kb * 32 + ((lane >> 4) * 8) + j;
            int n = nt * 16 + (lane & 15);
            Wf[g2] = f2bf(W[((size_t)s * D + k) * D + n]);
        }
    }
}

// ---------------------------------------------------------------------------
// Pass 2: per-bucket exclusive scan of row counts -> row_ptr2 (the exact
// format gather_gemm consumes: 513 entries/bucket, bucket base c*CAPB) and
// row_wptr (fill cursors for the place pass). Wave __shfl_up scan + 8 wave
// sums: ONE barrier instead of the old 18-barrier 512-wide scans.
// No row padding: gather's inner loop already zero-guards lanes >= m.
// ---------------------------------------------------------------------------
__global__ __launch_bounds__(512) void scan_rows(
    const int* __restrict__ row_cnt, int* __restrict__ row_ptr2,
    int* __restrict__ row_wptr)
{
    __shared__ int wsum[8];
    int c    = blockIdx.x;
    int tid  = threadIdx.x;
    int lane = tid & 63;
    int w    = tid >> 6;
    int grow = c * 512 + tid;
    int cnt  = (grow < NTOT) ? row_cnt[grow] : 0;

    int v = cnt;                                 // wave inclusive scan
    #pragma unroll
    for (int d = 1; d < 64; d <<= 1) {
        int t = __shfl_up(v, d);
        v += (lane >= d) ? t : 0;
    }
    if (lane == 63) wsum[w] = v;
    __syncthreads();
    int base = c * CAPB;
    #pragma unroll
    for (int i = 0; i < 8; ++i) base += (i < w) ? wsum[i] : 0;

    int start = base + v - cnt;
    row_ptr2[c * 513 + tid] = start;
    if (grow < NTOT) row_wptr[grow] = start;
    if (tid == 511) row_ptr2[c * 513 + 512] = base + v;
}

// ---------------------------------------------------------------------------
// Pass 3: PLACE. One streaming read of edges; slot from a diffuse per-row
// atomic cursor; 4B packed write (bf16(val)<<16 | col). The 10.8 MB sortedB
// region is L2/LLC-resident, so the scattered 4B writes merge before HBM.
// Replaces the 31 MB sortedA round-trip + LDS-staged scatter + register-
// staged bucket re-sort of the previous version.
// ---------------------------------------------------------------------------
__global__ __launch_bounds__(512) void place(
    const int* __restrict__ rows, const int* __restrict__ cols,
    const float* __restrict__ vals, int* __restrict__ row_wptr,
    unsigned int* __restrict__ sortedB)
{
    int base = blockIdx.x * 2048 + threadIdx.x;
    #pragma unroll
    for (int i = 0; i < 4; ++i) {
        int idx = base + i * 512;
        if (idx < E_TOT) {
            int s    = idx / N_EDGES;
            int grow = s * N_NODES + rows[idx];
            int pos  = atomicAdd(&row_wptr[grow], 1);
            sortedB[pos] = ((unsigned int)f2bf(vals[idx]) << 16)
                         | (unsigned int)cols[idx];
        }
    }
}

// ---------------------------------------------------------------------------
// FUSED gather + MFMA GEMM (proven R11, untouched). Block = 16 output nodes;
// 4 waves gather 48 rows into a 12.7 KB LDS tile, one barrier, then 24
// MFMAs/wave with fused bias+relu. Inner loop zero-guards lanes >= m, so
// unpadded rows (any edge count) are handled correctly.
// ---------------------------------------------------------------------------
__global__ __launch_bounds__(256) void gather_gemm(
    const unsigned short* __restrict__ xb, const int* __restrict__ row_ptr2,
    const unsigned int* __restrict__ sortedB,
    const unsigned short* __restrict__ Wf,
    const float* __restrict__ bias, float* __restrict__ out)
{
    __shared__ unsigned short ys[48 * LDSTR];    // 12.7 KB
    __shared__ int rs[48], re[48];
    const int tid  = threadIdx.x;
    const int w    = tid >> 6;
    const int lane = tid & 63;
    const int m0   = blockIdx.x * 16;

    if (tid < 48) {
        int grow = (tid >> 4) * N_NODES + m0 + (tid & 15);
        int rpi  = (grow >> 9) * 513 + (grow & 511);
        rs[tid] = row_ptr2[rpi];
        re[tid] = row_ptr2[rpi + 1];
    }
    __syncthreads();

    // ---- phase 1: gather 12 rows per wave ----
    const int hh = lane >> 5;                    // half index
    const int u  = lane & 31;                    // cols 4u..4u+3
    for (int r = w; r < 48; r += 4) {
        int start = rs[r], end = re[r];
        f32x2 accA = {0.f, 0.f}, accB = {0.f, 0.f};
        for (int j = start; j < end; j += 64) {
            int m = end - j; if (m > 64) m = 64;
            unsigned int ev = (lane < m) ? sortedB[j + lane] : 0u;
            for (int t = 0; t < m; t += 4) {
                unsigned int e0 = (unsigned int)__shfl((int)ev, t + hh);
                unsigned int e1 = (unsigned int)__shfl((int)ev, t + 2 + hh);
                float v0 = __uint_as_float(e0 & 0xFFFF0000u);
                float v1 = __uint_as_float(e1 & 0xFFFF0000u);
                uint2 X0 = *((const uint2*)(xb + (size_t)(e0 & 0xFFFFu) * D) + u);
                uint2 X1 = *((const uint2*)(xb + (size_t)(e1 & 0xFFFFu) * D) + u);
                f32x2 xa0 = {__uint_as_float(X0.x << 16),
                             __uint_as_float(X0.x & 0xFFFF0000u)};
                f32x2 xb0 = {__uint_as_float(X0.y << 16),
                             __uint_as_float(X0.y & 0xFFFF0000u)};
                f32x2 xa1 = {__uint_as_float(X1.x << 16),
                             __uint_as_float(X1.x & 0xFFFF0000u)};
                f32x2 xb1 = {__uint_as_float(X1.y << 16),
                             __uint_as_float(X1.y & 0xFFFF0000u)};
                accA += v0 * xa0;                // v_pk_fma_f32
                accB += v0 * xb0;
                accA += v1 * xa1;
                accB += v1 * xb1;
            }
        }
        float a0 = accA.x, a1 = accA.y, a2 = accB.x, a3 = accB.y;
        a0 += __shfl_xor(a0, 32);
        a1 += __shfl_xor(a1, 32);
        a2 += __shfl_xor(a2, 32);
        a3 += __shfl_xor(a3, 32);
        if (hh == 0) {
            uint2 o;
            o.x = (unsigned int)f2bf(a0) | ((unsigned int)f2bf(a1) << 16);
            o.y = (unsigned int)f2bf(a2) | ((unsigned int)f2bf(a3) << 16);
            *(uint2*)(ys + r * LDSTR + u * 4) = o;   // 8B-aligned, 2-way free
        }
    }
    __syncthreads();

    // ---- phase 2: MFMA GEMM, wave w -> nt {2w, 2w+1} ----
    const int quad = lane >> 4;
    const int l16  = lane & 15;
    const int nt0  = w * 2;
    f32x4 acc0 = {0.f, 0.f, 0.f, 0.f}, acc1 = {0.f, 0.f, 0.f, 0.f};

    #pragma unroll
    for (int s = 0; s < N_SUP; ++s) {
        #pragma unroll
        for (int kb = 0; kb < 4; ++kb) {
            union { uint2 q[2]; s16x8 v; } A;
            const unsigned short* ap = ys + (s * 16 + l16) * LDSTR
                                          + kb * 32 + quad * 8;
            A.q[0] = *(const uint2*)ap;          // 8B-aligned LDS reads
            A.q[1] = *(const uint2*)(ap + 4);
            const unsigned short* wf = Wf + (size_t)((s * 4 + kb) * 8 + nt0) * 64 * 8
                                          + lane * 8;
            s16x8 b0 = *(const s16x8*)wf;
            s16x8 b1 = *(const s16x8*)(wf + 64 * 8);
            acc0 = __builtin_amdgcn_mfma_f32_16x16x32_bf16(A.v, b0, acc0, 0, 0, 0);
            acc1 = __builtin_amdgcn_mfma_f32_16x16x32_bf16(A.v, b1, acc1, 0, 0, 0);
        }
    }

    #pragma unroll
    for (int p = 0; p < 2; ++p) {
        int col = (nt0 + p) * 16 + l16;
        float bv = bias[col];
        f32x4 a = p ? acc1 : acc0;
        #pragma unroll
        for (int r = 0; r < 4; ++r) {
            int row = m0 + quad * 4 + r;
            out[(size_t)row * D + col] = fmaxf(a[r] + bv, 0.f);
        }
    }
}

extern "C" void kernel_launch(void* const* d_in, const int* in_sizes, int n_in,
                              void* d_out, int out_size, void* d_ws, size_t ws_size,
                              hipStream_t stream)
{
    const float* x         = (const float*)d_in[0];
    const int*   edge_rows = (const int*)  d_in[1];
    const int*   edge_cols = (const int*)  d_in[2];
    const float* edge_vals = (const float*)d_in[3];
    const float* weights   = (const float*)d_in[4];
    const float* bias      = (const float*)d_in[5];
    float* out = (float*)d_out;

    // workspace layout (256B aligned), ~26 MB total
    char* ws = (char*)d_ws;
    size_t off = 0;
    auto alloc = [&](size_t bytes) -> char* {
        char* p = ws + off;
        off += (bytes + 255) & ~(size_t)255;
        return p;
    };
    int*            row_cnt  = (int*)            alloc((size_t)NTOT * 4);
    int*            row_wptr = (int*)            alloc((size_t)NTOT * 4);
    int*            row_ptr2 = (int*)            alloc((size_t)NC * 513 * 4);
    unsigned short* xb       = (unsigned short*) alloc((size_t)N_NODES * D * 2);
    unsigned short* Wf       = (unsigned short*) alloc((size_t)N_SUP * D * D * 2);
    unsigned int*   sortedB  = (unsigned int*)   alloc((size_t)(NC + 1) * CAPB * 4);

    hipMemsetAsync(row_cnt, 0, (size_t)NTOT * 4, stream);
    count_convert<<<CBLKS + XCBLKS + WBLKS, 512, 0, stream>>>(
        edge_rows, row_cnt, (const float4*)x, (ushort4*)xb, weights, Wf);
    scan_rows<<<NC, 512, 0, stream>>>(row_cnt, row_ptr2, row_wptr);
    place<<<CBLKS, 512, 0, stream>>>(edge_rows, edge_cols, edge_vals,
                                     row_wptr, sortedB);
    gather_gemm<<<N_NODES / 16, 256, 0, stream>>>(xb, row_ptr2, sortedB,
                                                  Wf, bias, out);
}

// Round 2
// 327.187 us; speedup vs baseline: 1.1575x; 1.1575x over previous
//
#include <hip/hip_runtime.h>

#define N_NODES 50000
#define N_EDGES 640000
#define N_SUP   3
#define D       128
#define NTOT    150000                   // 3 * 50000 global rows
#define E_TOT   1920000
#define NC      293                      // 512-row buckets (grow>>9)
#define CAPB    9216                     // per-bucket slot stride (mean 6553, +32 sigma)
#define CBLKS   938                      // ceil(E_TOT / 2048) count/place chunks
#define NSHARD  8                        // destination shards == XCDs
#define SHROWS  (NTOT / NSHARD)          // 18750 rows per shard (~1.35 MB slice)
#define XCBLKS  3125                     // (50000*128/4)/512 x-convert blocks
#define WBLKS   96                       // 49152/512 W-pack blocks
#define LDSTR   132                      // LDS row stride in shorts (128+4 pad)

typedef __attribute__((ext_vector_type(2))) float f32x2;
typedef __attribute__((ext_vector_type(4))) float f32x4;
typedef __attribute__((ext_vector_type(8))) short s16x8;

__device__ __forceinline__ unsigned short f2bf(float f) {   // RNE
    unsigned int u = __float_as_uint(f);
    u += 0x7FFFu + ((u >> 16) & 1u);
    return (unsigned short)(u >> 16);
}

// ---------------------------------------------------------------------------
// Pass 1: per-row edge COUNT (diffuse atomics over 150K counters), fused
// with the x->bf16 and W->fragment converts.
// ---------------------------------------------------------------------------
__global__ __launch_bounds__(512) void count_convert(
    const int* __restrict__ rows, int* __restrict__ row_cnt,
    const float4* __restrict__ x, ushort4* __restrict__ xb,
    const float* __restrict__ W, unsigned short* __restrict__ Wf)
{
    int tid = threadIdx.x;

    if (blockIdx.x < CBLKS) {                    // -------- count path ------
        int base = blockIdx.x * 2048 + tid;
        #pragma unroll
        for (int i = 0; i < 4; ++i) {
            int idx = base + i * 512;
            if (idx < E_TOT) {
                int s = idx / N_EDGES;           // magic-mul, cheap
                atomicAdd(&row_cnt[s * N_NODES + rows[idx]], 1);
            }
        }
        return;
    }

    int gid = (blockIdx.x - CBLKS) * 512 + tid;  // -------- convert path ----
    if (gid < N_NODES * D / 4) {                 // x -> bf16
        float4 v = x[gid];
        ushort4 o;
        o.x = f2bf(v.x); o.y = f2bf(v.y); o.z = f2bf(v.z); o.w = f2bf(v.w);
        xb[gid] = o;
    } else {                                     // W -> MFMA B-fragment order
        int g2 = gid - N_NODES * D / 4;
        if (g2 < N_SUP * D * D) {
            int j    = g2 & 7;
            int lane = (g2 >> 3) & 63;
            int rest = g2 >> 9;
            int nt = rest & 7, kb = (rest >> 3) & 3, s = rest >> 5;
            int k = kb * 32 + ((lane >> 4) * 8) + j;
            int n = nt * 16 + (lane & 15);
            Wf[g2] = f2bf(W[((size_t)s * D + k) * D + n]);
        }
    }
}

// ---------------------------------------------------------------------------
// Pass 2: per-bucket exclusive scan of row counts -> row_ptr2 (the format
// gather_gemm consumes: 513 entries/bucket, bucket base c*CAPB) and row_wptr
// (fill cursors for the place pass). Wave __shfl_up scan + 8 wave sums.
// ---------------------------------------------------------------------------
__global__ __launch_bounds__(512) void scan_rows(
    const int* __restrict__ row_cnt, int* __restrict__ row_ptr2,
    int* __restrict__ row_wptr)
{
    __shared__ int wsum[8];
    int c    = blockIdx.x;
    int tid  = threadIdx.x;
    int lane = tid & 63;
    int w    = tid >> 6;
    int grow = c * 512 + tid;
    int cnt  = (grow < NTOT) ? row_cnt[grow] : 0;

    int v = cnt;                                 // wave inclusive scan
    #pragma unroll
    for (int d = 1; d < 64; d <<= 1) {
        int t = __shfl_up(v, d);
        v += (lane >= d) ? t : 0;
    }
    if (lane == 63) wsum[w] = v;
    __syncthreads();
    int base = c * CAPB;
    #pragma unroll
    for (int i = 0; i < 8; ++i) base += (i < w) ? wsum[i] : 0;

    int start = base + v - cnt;
    row_ptr2[c * 513 + tid] = start;
    if (grow < NTOT) row_wptr[grow] = start;
    if (tid == 511) row_ptr2[c * 513 + 512] = base + v;
}

// ---------------------------------------------------------------------------
// Pass 3: PLACE, XCD-SHARDED. Round 1's flat version hit 12x write
// amplification (WRITE_SIZE 128 MB for a 7.7 MB payload): scattered 4B
// stores from all 8 XCDs into the whole 10.8 MB sortedB region evicted
// partial lines to HBM. Fix: shard destination rows 8 ways; block b handles
// edge chunk b>>3 filtered to shard b&7. Hardware assigns blockIdx->XCD
// round-robin (%8), so each XCD's L2 only writes its own ~1.35 MB slice --
// lines stay resident until fully written, HBM writes drop to compulsory.
// rows[] is re-streamed 8x (LLC-resident, cheap); cols/vals read once under
// the predicate.
// ---------------------------------------------------------------------------
__global__ __launch_bounds__(512) void place(
    const int* __restrict__ rows, const int* __restrict__ cols,
    const float* __restrict__ vals, int* __restrict__ row_wptr,
    unsigned int* __restrict__ sortedB)
{
    int shard = blockIdx.x & (NSHARD - 1);       // == XCD id (round-robin)
    int chunk = blockIdx.x >> 3;
    int lo    = shard * SHROWS;
    int hi    = lo + SHROWS;
    int base  = chunk * 2048 + threadIdx.x;

    #pragma unroll
    for (int i = 0; i < 4; ++i) {
        int idx = base + i * 512;
        if (idx < E_TOT) {
            int s    = idx / N_EDGES;
            int grow = s * N_NODES + rows[idx];
            if (grow >= lo && grow < hi) {
                int pos = atomicAdd(&row_wptr[grow], 1);
                sortedB[pos] = ((unsigned int)f2bf(vals[idx]) << 16)
                             | (unsigned int)cols[idx];
            }
        }
    }
}

// ---------------------------------------------------------------------------
// FUSED gather + MFMA GEMM (proven, untouched). Block = 16 output nodes;
// 4 waves gather 48 rows into a 12.7 KB LDS tile, one barrier, then 24
// MFMAs/wave with fused bias+relu. Inner loop zero-guards lanes >= m, so
// unpadded rows (any edge count) are handled correctly.
// ---------------------------------------------------------------------------
__global__ __launch_bounds__(256) void gather_gemm(
    const unsigned short* __restrict__ xb, const int* __restrict__ row_ptr2,
    const unsigned int* __restrict__ sortedB,
    const unsigned short* __restrict__ Wf,
    const float* __restrict__ bias, float* __restrict__ out)
{
    __shared__ unsigned short ys[48 * LDSTR];    // 12.7 KB
    __shared__ int rs[48], re[48];
    const int tid  = threadIdx.x;
    const int w    = tid >> 6;
    const int lane = tid & 63;
    const int m0   = blockIdx.x * 16;

    if (tid < 48) {
        int grow = (tid >> 4) * N_NODES + m0 + (tid & 15);
        int rpi  = (grow >> 9) * 513 + (grow & 511);
        rs[tid] = row_ptr2[rpi];
        re[tid] = row_ptr2[rpi + 1];
    }
    __syncthreads();

    // ---- phase 1: gather 12 rows per wave ----
    const int hh = lane >> 5;                    // half index
    const int u  = lane & 31;                    // cols 4u..4u+3
    for (int r = w; r < 48; r += 4) {
        int start = rs[r], end = re[r];
        f32x2 accA = {0.f, 0.f}, accB = {0.f, 0.f};
        for (int j = start; j < end; j += 64) {
            int m = end - j; if (m > 64) m = 64;
            unsigned int ev = (lane < m) ? sortedB[j + lane] : 0u;
            for (int t = 0; t < m; t += 4) {
                unsigned int e0 = (unsigned int)__shfl((int)ev, t + hh);
                unsigned int e1 = (unsigned int)__shfl((int)ev, t + 2 + hh);
                float v0 = __uint_as_float(e0 & 0xFFFF0000u);
                float v1 = __uint_as_float(e1 & 0xFFFF0000u);
                uint2 X0 = *((const uint2*)(xb + (size_t)(e0 & 0xFFFFu) * D) + u);
                uint2 X1 = *((const uint2*)(xb + (size_t)(e1 & 0xFFFFu) * D) + u);
                f32x2 xa0 = {__uint_as_float(X0.x << 16),
                             __uint_as_float(X0.x & 0xFFFF0000u)};
                f32x2 xb0 = {__uint_as_float(X0.y << 16),
                             __uint_as_float(X0.y & 0xFFFF0000u)};
                f32x2 xa1 = {__uint_as_float(X1.x << 16),
                             __uint_as_float(X1.x & 0xFFFF0000u)};
                f32x2 xb1 = {__uint_as_float(X1.y << 16),
                             __uint_as_float(X1.y & 0xFFFF0000u)};
                accA += v0 * xa0;                // v_pk_fma_f32
                accB += v0 * xb0;
                accA += v1 * xa1;
                accB += v1 * xb1;
            }
        }
        float a0 = accA.x, a1 = accA.y, a2 = accB.x, a3 = accB.y;
        a0 += __shfl_xor(a0, 32);
        a1 += __shfl_xor(a1, 32);
        a2 += __shfl_xor(a2, 32);
        a3 += __shfl_xor(a3, 32);
        if (hh == 0) {
            uint2 o;
            o.x = (unsigned int)f2bf(a0) | ((unsigned int)f2bf(a1) << 16);
            o.y = (unsigned int)f2bf(a2) | ((unsigned int)f2bf(a3) << 16);
            *(uint2*)(ys + r * LDSTR + u * 4) = o;   // 8B-aligned, 2-way free
        }
    }
    __syncthreads();

    // ---- phase 2: MFMA GEMM, wave w -> nt {2w, 2w+1} ----
    const int quad = lane >> 4;
    const int l16  = lane & 15;
    const int nt0  = w * 2;
    f32x4 acc0 = {0.f, 0.f, 0.f, 0.f}, acc1 = {0.f, 0.f, 0.f, 0.f};

    #pragma unroll
    for (int s = 0; s < N_SUP; ++s) {
        #pragma unroll
        for (int kb = 0; kb < 4; ++kb) {
            union { uint2 q[2]; s16x8 v; } A;
            const unsigned short* ap = ys + (s * 16 + l16) * LDSTR
                                          + kb * 32 + quad * 8;
            A.q[0] = *(const uint2*)ap;          // 8B-aligned LDS reads
            A.q[1] = *(const uint2*)(ap + 4);
            const unsigned short* wf = Wf + (size_t)((s * 4 + kb) * 8 + nt0) * 64 * 8
                                          + lane * 8;
            s16x8 b0 = *(const s16x8*)wf;
            s16x8 b1 = *(const s16x8*)(wf + 64 * 8);
            acc0 = __builtin_amdgcn_mfma_f32_16x16x32_bf16(A.v, b0, acc0, 0, 0, 0);
            acc1 = __builtin_amdgcn_mfma_f32_16x16x32_bf16(A.v, b1, acc1, 0, 0, 0);
        }
    }

    #pragma unroll
    for (int p = 0; p < 2; ++p) {
        int col = (nt0 + p) * 16 + l16;
        float bv = bias[col];
        f32x4 a = p ? acc1 : acc0;
        #pragma unroll
        for (int r = 0; r < 4; ++r) {
            int row = m0 + quad * 4 + r;
            out[(size_t)row * D + col] = fmaxf(a[r] + bv, 0.f);
        }
    }
}

extern "C" void kernel_launch(void* const* d_in, const int* in_sizes, int n_in,
                              void* d_out, int out_size, void* d_ws, size_t ws_size,
                              hipStream_t stream)
{
    const float* x         = (const float*)d_in[0];
    const int*   edge_rows = (const int*)  d_in[1];
    const int*   edge_cols = (const int*)  d_in[2];
    const float* edge_vals = (const float*)d_in[3];
    const float* weights   = (const float*)d_in[4];
    const float* bias      = (const float*)d_in[5];
    float* out = (float*)d_out;

    // workspace layout (256B aligned), ~26 MB total
    char* ws = (char*)d_ws;
    size_t off = 0;
    auto alloc = [&](size_t bytes) -> char* {
        char* p = ws + off;
        off += (bytes + 255) & ~(size_t)255;
        return p;
    };
    int*            row_cnt  = (int*)            alloc((size_t)NTOT * 4);
    int*            row_wptr = (int*)            alloc((size_t)NTOT * 4);
    int*            row_ptr2 = (int*)            alloc((size_t)NC * 513 * 4);
    unsigned short* xb       = (unsigned short*) alloc((size_t)N_NODES * D * 2);
    unsigned short* Wf       = (unsigned short*) alloc((size_t)N_SUP * D * D * 2);
    unsigned int*   sortedB  = (unsigned int*)   alloc((size_t)(NC + 1) * CAPB * 4);

    hipMemsetAsync(row_cnt, 0, (size_t)NTOT * 4, stream);
    count_convert<<<CBLKS + XCBLKS + WBLKS, 512, 0, stream>>>(
        edge_rows, row_cnt, (const float4*)x, (ushort4*)xb, weights, Wf);
    scan_rows<<<NC, 512, 0, stream>>>(row_cnt, row_ptr2, row_wptr);
    place<<<NSHARD * CBLKS, 512, 0, stream>>>(edge_rows, edge_cols, edge_vals,
                                              row_wptr, sortedB);
    gather_gemm<<<N_NODES / 16, 256, 0, stream>>>(xb, row_ptr2, sortedB,
                                                  Wf, bias, out);
}

// Round 3
// 199.146 us; speedup vs baseline: 1.9017x; 1.6429x over previous
//
#include <hip/hip_runtime.h>

#define N_NODES 50000
#define N_EDGES 640000
#define N_SUP   3
#define D       128
#define NTOT    150000                   // 3 * 50000 global rows
#define E_TOT   1920000
#define NC      293                      // 512-row coarse buckets (grow>>9)
#define CAPC    7680                     // per-bucket cap: mean 6553 + ~14 sigma
#define CTILE   2048
#define CTPS    313                      // ceil(640000/2048) tiles per support
#define SBLKS   (N_SUP * CTPS)           // 939 scatter blocks
#define XCBLKS  3125                     // (50000*128/4)/512 x-convert blocks
#define WBLKS   96                       // 49152/512 W-pack blocks
#define LDSTR   132                      // LDS row stride in shorts (128+4 pad)

typedef __attribute__((ext_vector_type(2))) float f32x2;
typedef __attribute__((ext_vector_type(4))) float f32x4;
typedef __attribute__((ext_vector_type(8))) short s16x8;

__device__ __forceinline__ unsigned short f2bf(float f) {   // RNE
    unsigned int u = __float_as_uint(f);
    u += 0x7FFFu + ((u >> 16) & 1u);
    return (unsigned short)(u >> 16);
}

// ---------------------------------------------------------------------------
// Pass 1: fused prep + coarse scatter (R0 structure, tuned). Edges are
// ranked and staged in LDS sorted by 512-row bucket with precomputed
// absolute destinations, so global writes are dense runs (no per-edge
// global atomics, no reliance on XCD mapping). Changes vs R0:
//   - coarse_wptr padded 1 counter/cacheline (stride 16) -> no hot lines
//   - 512-wide LDS scan replaced by wave shfl scan (5 barriers vs ~21)
//   - val converted to bf16 here; intermediate split u32 meta + u16 val
//     (6 B/edge instead of 8)
// meta = (local_row<<16) | col.
// ---------------------------------------------------------------------------
__global__ __launch_bounds__(512) void prep_scatter(
    const int* __restrict__ rows, const int* __restrict__ cols,
    const float* __restrict__ vals, int* __restrict__ coarse_wptr,
    unsigned int* __restrict__ sortedM, unsigned short* __restrict__ sortedV,
    const float4* __restrict__ x, ushort4* __restrict__ xb,
    const float* __restrict__ W, unsigned short* __restrict__ Wf)
{
    int tid = threadIdx.x;

    if (blockIdx.x >= SBLKS) {                   // -------- convert path ----
        int gid = (blockIdx.x - SBLKS) * 512 + tid;
        if (gid < N_NODES * D / 4) {             // x -> bf16
            float4 v = x[gid];
            ushort4 o;
            o.x = f2bf(v.x); o.y = f2bf(v.y); o.z = f2bf(v.z); o.w = f2bf(v.w);
            xb[gid] = o;
        } else {                                 // W -> MFMA B-fragment order
            int g2 = gid - N_NODES * D / 4;
            if (g2 < N_SUP * D * D) {
                int j    = g2 & 7;
                int lane = (g2 >> 3) & 63;
                int rest = g2 >> 9;
                int nt = rest & 7, kb = (rest >> 3) & 3, s = rest >> 5;
                int k = kb * 32 + ((lane >> 4) * 8) + j;
                int n = nt * 16 + (lane & 15);
                Wf[g2] = f2bf(W[((size_t)s * D + k) * D + n]);
            }
        }
        return;
    }

    // ------------------------------- scatter path -------------------------
    __shared__ int            h[512];            // bucket histogram
    __shared__ int            toff[512];         // tile-local bucket offsets
    __shared__ int            gbase[512];        // global bucket bases
    __shared__ int            wsum[8];
    __shared__ unsigned int   stageM[CTILE];     // 8 KB bucket-sorted meta
    __shared__ unsigned short stageV[CTILE];     // 4 KB bucket-sorted bf16 val
    __shared__ unsigned int   dst[CTILE];        // 8 KB absolute dests

    const int lane = tid & 63;
    const int w    = tid >> 6;

    h[tid] = 0;
    __syncthreads();

    int s  = blockIdx.x / CTPS;
    int tb = (blockIdx.x % CTPS) * CTILE;
    int n  = N_EDGES - tb; if (n > CTILE) n = CTILE;
    const int*   rp = rows + (size_t)s * N_EDGES + tb;
    const int*   cp = cols + (size_t)s * N_EDGES + tb;
    const float* vp = vals + (size_t)s * N_EDGES + tb;

    int bk[4], rk[4]; unsigned int edM[4]; unsigned short edV[4];
    #pragma unroll
    for (int i = 0; i < 4; ++i) {
        int idx = tid + i * 512;
        bk[i] = -1;
        if (idx < n) {
            int grow = s * N_NODES + rp[idx];
            bk[i] = grow >> 9;
            rk[i] = atomicAdd(&h[bk[i]], 1);     // within-tile bucket rank
            edM[i] = ((unsigned int)(grow & 511) << 16) | (unsigned int)cp[idx];
            edV[i] = f2bf(vp[idx]);
        }
    }
    __syncthreads();
    int cntb = h[tid];                           // this thread's bucket count

    int v = cntb;                                // wave inclusive scan
    #pragma unroll
    for (int d = 1; d < 64; d <<= 1) {
        int t = __shfl_up(v, d);
        v += (lane >= d) ? t : 0;
    }
    if (lane == 63) wsum[w] = v;
    __syncthreads();
    int add = 0;
    #pragma unroll
    for (int i = 0; i < 8; ++i) add += (i < w) ? wsum[i] : 0;
    int incl = v + add;

    toff[tid]  = incl - cntb;                    // tile-local exclusive
    gbase[tid] = (cntb > 0) ? atomicAdd(&coarse_wptr[tid * 16], cntb) : 0;
    __syncthreads();

    #pragma unroll
    for (int i = 0; i < 4; ++i) {
        if (bk[i] >= 0) {
            int slot  = toff[bk[i]] + rk[i];
            int gslot = gbase[bk[i]] + rk[i];
            stageM[slot] = edM[i];
            stageV[slot] = edV[i];
            dst[slot] = (gslot < CAPC)
                      ? (unsigned int)(bk[i] * CAPC + gslot)
                      : 0xFFFFFFFFu;             // never at +14 sigma
        }
    }
    __syncthreads();
    for (int j = tid; j < n; j += 512) {         // coalesced run writes
        unsigned int d = dst[j];
        if (d != 0xFFFFFFFFu) {
            sortedM[d] = stageM[j];
            sortedV[d] = stageV[j];
        }
    }
}

// ---------------------------------------------------------------------------
// Pass 2: fine sort, ONE block per bucket. Loads the bucket's edges into
// registers (<=15/thread), LDS histogram + wave-shfl scan (1 barrier),
// scatter from registers. Changes vs R0: unpadded rows (gather zero-guards
// lanes >= m, proven R1/R2), no zero-fill loop, 6 B/edge input, bf16 val
// already converted.
// row_ptr2: 513 entries/bucket, last = bucket end.
// ---------------------------------------------------------------------------
__global__ __launch_bounds__(512) void bucket_sort(
    const int* __restrict__ coarse_wptr,
    const unsigned int* __restrict__ sortedM,
    const unsigned short* __restrict__ sortedV,
    int* __restrict__ row_ptr2, unsigned int* __restrict__ sortedB)
{
    int c   = blockIdx.x;
    int cnt = coarse_wptr[c * 16];
    if (cnt > CAPC) cnt = CAPC;

    __shared__ int hist[512];
    __shared__ int rank[512];
    __shared__ int wsum[8];
    int tid  = threadIdx.x;
    int lane = tid & 63;
    int w    = tid >> 6;
    hist[tid] = 0;

    const unsigned int*   srcM = sortedM + (size_t)c * CAPC;
    const unsigned short* srcV = sortedV + (size_t)c * CAPC;
    unsigned int   m[15];
    unsigned short vv[15];
    #pragma unroll
    for (int k = 0; k < 15; ++k) {               // independent loads
        int idx = tid + k * 512;
        if (idx < cnt) { m[k] = srcM[idx]; vv[k] = srcV[idx]; }
    }
    __syncthreads();
    #pragma unroll
    for (int k = 0; k < 15; ++k) {
        int idx = tid + k * 512;
        if (idx < cnt) atomicAdd(&hist[m[k] >> 16], 1);
    }
    __syncthreads();

    int cntb = hist[tid];
    int v = cntb;                                // wave inclusive scan
    #pragma unroll
    for (int d = 1; d < 64; d <<= 1) {
        int t = __shfl_up(v, d);
        v += (lane >= d) ? t : 0;
    }
    if (lane == 63) wsum[w] = v;
    __syncthreads();
    int add = 0;
    #pragma unroll
    for (int i = 0; i < 8; ++i) add += (i < w) ? wsum[i] : 0;
    int incl = v + add;

    int start = c * CAPC + incl - cntb;          // exclusive, bucket-based
    rank[tid] = start;
    row_ptr2[c * 513 + tid] = start;
    if (tid == 511) row_ptr2[c * 513 + 512] = c * CAPC + incl;
    __syncthreads();

    #pragma unroll
    for (int k = 0; k < 15; ++k) {
        int idx = tid + k * 512;
        if (idx < cnt) {
            int r = atomicAdd(&rank[m[k] >> 16], 1);
            sortedB[r] = ((unsigned int)vv[k] << 16) | (m[k] & 0xFFFFu);
        }
    }
}

// ---------------------------------------------------------------------------
// FUSED gather + MFMA GEMM (proven, untouched). Block = 16 output nodes;
// 4 waves gather 48 rows into a 12.7 KB LDS tile, one barrier, then 24
// MFMAs/wave with fused bias+relu. Inner loop zero-guards lanes >= m, so
// unpadded rows (any edge count) are handled correctly.
// ---------------------------------------------------------------------------
__global__ __launch_bounds__(256) void gather_gemm(
    const unsigned short* __restrict__ xb, const int* __restrict__ row_ptr2,
    const unsigned int* __restrict__ sortedB,
    const unsigned short* __restrict__ Wf,
    const float* __restrict__ bias, float* __restrict__ out)
{
    __shared__ unsigned short ys[48 * LDSTR];    // 12.7 KB
    __shared__ int rs[48], re[48];
    const int tid  = threadIdx.x;
    const int w    = tid >> 6;
    const int lane = tid & 63;
    const int m0   = blockIdx.x * 16;

    if (tid < 48) {
        int grow = (tid >> 4) * N_NODES + m0 + (tid & 15);
        int rpi  = (grow >> 9) * 513 + (grow & 511);
        rs[tid] = row_ptr2[rpi];
        re[tid] = row_ptr2[rpi + 1];
    }
    __syncthreads();

    // ---- phase 1: gather 12 rows per wave ----
    const int hh = lane >> 5;                    // half index
    const int u  = lane & 31;                    // cols 4u..4u+3
    for (int r = w; r < 48; r += 4) {
        int start = rs[r], end = re[r];
        f32x2 accA = {0.f, 0.f}, accB = {0.f, 0.f};
        for (int j = start; j < end; j += 64) {
            int m = end - j; if (m > 64) m = 64;
            unsigned int ev = (lane < m) ? sortedB[j + lane] : 0u;
            for (int t = 0; t < m; t += 4) {
                unsigned int e0 = (unsigned int)__shfl((int)ev, t + hh);
                unsigned int e1 = (unsigned int)__shfl((int)ev, t + 2 + hh);
                float v0 = __uint_as_float(e0 & 0xFFFF0000u);
                float v1 = __uint_as_float(e1 & 0xFFFF0000u);
                uint2 X0 = *((const uint2*)(xb + (size_t)(e0 & 0xFFFFu) * D) + u);
                uint2 X1 = *((const uint2*)(xb + (size_t)(e1 & 0xFFFFu) * D) + u);
                f32x2 xa0 = {__uint_as_float(X0.x << 16),
                             __uint_as_float(X0.x & 0xFFFF0000u)};
                f32x2 xb0 = {__uint_as_float(X0.y << 16),
                             __uint_as_float(X0.y & 0xFFFF0000u)};
                f32x2 xa1 = {__uint_as_float(X1.x << 16),
                             __uint_as_float(X1.x & 0xFFFF0000u)};
                f32x2 xb1 = {__uint_as_float(X1.y << 16),
                             __uint_as_float(X1.y & 0xFFFF0000u)};
                accA += v0 * xa0;                // v_pk_fma_f32
                accB += v0 * xb0;
                accA += v1 * xa1;
                accB += v1 * xb1;
            }
        }
        float a0 = accA.x, a1 = accA.y, a2 = accB.x, a3 = accB.y;
        a0 += __shfl_xor(a0, 32);
        a1 += __shfl_xor(a1, 32);
        a2 += __shfl_xor(a2, 32);
        a3 += __shfl_xor(a3, 32);
        if (hh == 0) {
            uint2 o;
            o.x = (unsigned int)f2bf(a0) | ((unsigned int)f2bf(a1) << 16);
            o.y = (unsigned int)f2bf(a2) | ((unsigned int)f2bf(a3) << 16);
            *(uint2*)(ys + r * LDSTR + u * 4) = o;   // 8B-aligned, 2-way free
        }
    }
    __syncthreads();

    // ---- phase 2: MFMA GEMM, wave w -> nt {2w, 2w+1} ----
    const int quad = lane >> 4;
    const int l16  = lane & 15;
    const int nt0  = w * 2;
    f32x4 acc0 = {0.f, 0.f, 0.f, 0.f}, acc1 = {0.f, 0.f, 0.f, 0.f};

    #pragma unroll
    for (int s = 0; s < N_SUP; ++s) {
        #pragma unroll
        for (int kb = 0; kb < 4; ++kb) {
            union { uint2 q[2]; s16x8 v; } A;
            const unsigned short* ap = ys + (s * 16 + l16) * LDSTR
                                          + kb * 32 + quad * 8;
            A.q[0] = *(const uint2*)ap;          // 8B-aligned LDS reads
            A.q[1] = *(const uint2*)(ap + 4);
            const unsigned short* wf = Wf + (size_t)((s * 4 + kb) * 8 + nt0) * 64 * 8
                                          + lane * 8;
            s16x8 b0 = *(const s16x8*)wf;
            s16x8 b1 = *(const s16x8*)(wf + 64 * 8);
            acc0 = __builtin_amdgcn_mfma_f32_16x16x32_bf16(A.v, b0, acc0, 0, 0, 0);
            acc1 = __builtin_amdgcn_mfma_f32_16x16x32_bf16(A.v, b1, acc1, 0, 0, 0);
        }
    }

    #pragma unroll
    for (int p = 0; p < 2; ++p) {
        int col = (nt0 + p) * 16 + l16;
        float bv = bias[col];
        f32x4 a = p ? acc1 : acc0;
        #pragma unroll
        for (int r = 0; r < 4; ++r) {
            int row = m0 + quad * 4 + r;
            out[(size_t)row * D + col] = fmaxf(a[r] + bv, 0.f);
        }
    }
}

extern "C" void kernel_launch(void* const* d_in, const int* in_sizes, int n_in,
                              void* d_out, int out_size, void* d_ws, size_t ws_size,
                              hipStream_t stream)
{
    const float* x         = (const float*)d_in[0];
    const int*   edge_rows = (const int*)  d_in[1];
    const int*   edge_cols = (const int*)  d_in[2];
    const float* edge_vals = (const float*)d_in[3];
    const float* weights   = (const float*)d_in[4];
    const float* bias      = (const float*)d_in[5];
    float* out = (float*)d_out;

    // workspace layout (256B aligned), ~28 MB total
    char* ws = (char*)d_ws;
    size_t off = 0;
    auto alloc = [&](size_t bytes) -> char* {
        char* p = ws + off;
        off += (bytes + 255) & ~(size_t)255;
        return p;
    };
    int*            coarse_wptr = (int*)            alloc(512 * 16 * 4);
    int*            row_ptr2    = (int*)            alloc((size_t)NC * 513 * 4);
    unsigned short* xb          = (unsigned short*) alloc((size_t)N_NODES * D * 2);
    unsigned short* Wf          = (unsigned short*) alloc((size_t)N_SUP * D * D * 2);
    unsigned int*   sortedM     = (unsigned int*)   alloc((size_t)NC * CAPC * 4);
    unsigned short* sortedV     = (unsigned short*) alloc((size_t)NC * CAPC * 2);
    unsigned int*   sortedB     = (unsigned int*)   alloc((size_t)NC * CAPC * 4);

    hipMemsetAsync(coarse_wptr, 0, 512 * 16 * 4, stream);
    prep_scatter<<<SBLKS + XCBLKS + WBLKS, 512, 0, stream>>>(
        edge_rows, edge_cols, edge_vals, coarse_wptr, sortedM, sortedV,
        (const float4*)x, (ushort4*)xb, weights, Wf);
    bucket_sort <<<NC, 512, 0, stream>>>(coarse_wptr, sortedM, sortedV,
                                         row_ptr2, sortedB);
    gather_gemm<<<N_NODES / 16, 256, 0, stream>>>(xb, row_ptr2, sortedB,
                                                  Wf, bias, out);
}